// Round 1
// baseline (992.451 us; speedup 1.0000x reference)
//
#include <hip/hip_runtime.h>
#include <math.h>

// N=64, T=2048, E=512, A=256, D=512, S=64, O=80, H4=2048
// Key algebraic facts exploited (verified against reference semantics):
//  - att0 one-hot at t=0  -> attention mask = {t : 0 <= t < 10}; softmax max-shift cancels
//  - h=c=0 into both LSTM cells -> Whh* unused; f-gate rows of Wih* unused (sigmoid(f)*c = 0)
//  - conv(one-hot) = conv_w[a, 15-t]
//
// ws layout (floats):
//   XT0 @ 0       : 1088*64  in_lstm^T  (k<512: prenet p | 512..1024: context | 1024..1088: spkr)
//   G   @ 69632   : 6144*64  gates^T (compact rows: i | g | o), reused for both LSTM layers
//   XT1 @ 462848  : 2048*64  h1^T then h2^T
//   HID @ 593920  : 1024*64  prenet hidden^T
//   SPT @ 659456  : 512*64   sp^T
// total 692224 floats = 2.77 MB

__device__ __forceinline__ float sigmoidf_(float x){ return 1.0f/(1.0f+expf(-x)); }
__device__ __forceinline__ float softsignf_(float x){ return x/(1.0f+fabsf(x)); }

// hidden = relu(concat(input_dec, spkr) @ pre_W1 + pre_b1)   (K=144 -> J=1024, K-major W)
__global__ void hidden_kernel(const float* __restrict__ input_dec, const float* __restrict__ spkr,
                              const float* __restrict__ W, const float* __restrict__ b,
                              float* __restrict__ outT)
{
    const int tid = threadIdx.x;
    const int n = tid & 63;
    const int j = blockIdx.x * 4 + (tid >> 6);   // j < 1024
    float acc = 0.f;
    for (int k = 0; k < 144; ++k) {
        const float x = (k < 80) ? input_dec[n*80 + k] : spkr[n*64 + (k - 80)];
        acc = fmaf(x, W[k*1024 + j], acc);
    }
    acc += b[j];
    outT[j*64 + n] = fmaxf(acc, 0.f);
}

// sp = tanh(relu(speed*sp_W1 + sp_b1) @ sp_W2 + sp_b2)   (K=512 -> J=512, K-major W)
__global__ void sp_kernel(const float* __restrict__ speed, const float* __restrict__ sp_W1,
                          const float* __restrict__ sp_b1, const float* __restrict__ sp_W2,
                          const float* __restrict__ sp_b2, float* __restrict__ outT)
{
    const int tid = threadIdx.x;
    const int n = tid & 63;
    const int j = blockIdx.x * 4 + (tid >> 6);   // j < 512
    const float s = speed[n];
    float acc = 0.f;
    for (int d = 0; d < 512; ++d) {
        const float r = fmaxf(fmaf(s, sp_W1[d], sp_b1[d]), 0.f);
        acc = fmaf(r, sp_W2[d*512 + j], acc);
    }
    acc += sp_b2[j];
    outT[j*64 + n] = tanhf(acc);
}

// p = relu(hidden @ pre_W2 + pre_b2)   (K=1024 -> J=512, K-major W) -> XT0 rows [0,512)
__global__ void p_kernel(const float* __restrict__ hidT, const float* __restrict__ W,
                         const float* __restrict__ b, float* __restrict__ outT)
{
    const int tid = threadIdx.x;
    const int n = tid & 63;
    const int j = blockIdx.x * 4 + (tid >> 6);   // j < 512
    float acc = 0.f;
    for (int k = 0; k < 1024; ++k)
        acc = fmaf(hidT[k*64 + n], W[k*512 + j], acc);
    acc += b[j];
    outT[j*64 + n] = fmaxf(acc, 0.f);
}

// attention + context, one block per batch row n, 256 threads (= a index)
__global__ void attn_kernel(const float* __restrict__ input_enc,
                            const float* __restrict__ spkr,
                            const float* __restrict__ speed,
                            const int*   __restrict__ lengths,
                            const float* __restrict__ We,
                            const float* __restrict__ be,
                            const float* __restrict__ Ws,
                            const float* __restrict__ conv_w,
                            const float* __restrict__ w_proj,
                            const float* __restrict__ b_proj,
                            const float* __restrict__ W_speed,
                            const float* __restrict__ spT,
                            float* __restrict__ xT0,
                            float* __restrict__ out_ctx,
                            float* __restrict__ out_dec)
{
    const int n = blockIdx.x;
    const int a = threadIdx.x;               // 256 threads
    __shared__ float encs[10*512];           // 20 KB: enc rows t<10
    __shared__ float part[4][10];
    __shared__ float logit_s[10];
    __shared__ float att_s[10];

    const int L1 = lengths[n] - 1;
    const int tc = (L1 + 1 < 10) ? (L1 + 1) : 10;
    const float sn = speed[n];
    const float* enc_n = input_enc + (size_t)n * (2048*512);

    // stage first 10 timesteps (contiguous 5120 floats)
    for (int idx = a; idx < 10*512; idx += 256) encs[idx] = enc_n[idx];
    __syncthreads();

    // bias_spkr[a] = softsign(spkr_n @ Ws[:,a])
    float ds = 0.f;
    for (int s = 0; s < 64; ++s) ds = fmaf(spkr[n*64 + s], Ws[s*256 + a], ds);
    const float bspkr = softsignf_(ds);
    const float bspd  = sn * W_speed[a];
    const float bea   = be[a];
    const float wpa   = w_proj[a];

    // dt[t] = enc[t,:] @ We[:,a]   (We column a read once, broadcast enc from LDS)
    float dt[10];
    #pragma unroll
    for (int t = 0; t < 10; ++t) dt[t] = 0.f;
    for (int k = 0; k < 512; ++k) {
        const float w = We[k*256 + a];
        #pragma unroll
        for (int t = 0; t < 10; ++t) dt[t] = fmaf(encs[t*512 + k], w, dt[t]);
    }

    for (int t = 0; t < 10; ++t) {
        float e = softsignf_(dt[t] + bea);
        e += bspkr + conv_w[a*31 + (15 - t)] + bspd;
        float v = tanhf(e) * wpa;
        #pragma unroll
        for (int off = 32; off > 0; off >>= 1) v += __shfl_down(v, off);
        if ((a & 63) == 0) part[a >> 6][t] = v;
    }
    __syncthreads();
    if (a < 10) logit_s[a] = part[0][a] + part[1][a] + part[2][a] + part[3][a] + b_proj[0];
    __syncthreads();
    if (a == 0) {
        float mx = -1e30f;
        for (int t = 0; t < tc; ++t) mx = fmaxf(mx, logit_s[t]);
        float ssum = 0.f;
        for (int t = 0; t < tc; ++t) { att_s[t] = expf(logit_s[t] - mx); ssum += att_s[t]; }
        const float inv = 1.f / fmaxf(ssum, 1e-12f);
        for (int t = 0; t < tc; ++t) att_s[t] *= inv;
        for (int t = tc; t < 10; ++t) att_s[t] = 0.f;
    }
    __syncthreads();

    // context[n,e] = sum_t att[t] * (enc[t,e] + sp[n,e])
    for (int e0 = a; e0 < 512; e0 += 256) {
        const float spv = spT[e0*64 + n];
        float c = 0.f;
        for (int t = 0; t < tc; ++t) c = fmaf(att_s[t], encs[t*512 + e0] + spv, c);
        xT0[(512 + e0)*64 + n] = c;           // feed LSTM0
        out_ctx[n*512 + e0]   = c;            // output 1: context
        out_dec[n*2560 + 2048 + e0] = c;      // output 2: dec_output tail
    }
    if (a < 64) xT0[(1024 + a)*64 + n] = spkr[n*64 + a];
}

// big skinny GEMM: gates^T[jj,n] = x^T[:,n] . W[j(jj),:] + b1[j] + b2[j]
// W row-major (rows of length K). FSKIP: skip f-gate rows (jj>=2048 -> j=jj+2048).
// 16 rows/block (4 waves x 4 rows/thread), float4 W loads, coalesced x loads.
template<int K, bool FSKIP>
__global__ void gemm_big(const float* __restrict__ xT, const float* __restrict__ W,
                         const float* __restrict__ b1, const float* __restrict__ b2,
                         float* __restrict__ outT)
{
    const int tid = threadIdx.x;
    const int n = tid & 63;
    const int wv = __builtin_amdgcn_readfirstlane(tid >> 6);
    const int jj0 = blockIdx.x * 16 + wv * 4;
    const int j0  = (FSKIP && jj0 >= 2048) ? jj0 + 2048 : jj0;
    const float* Wr = W + (size_t)j0 * K;
    float acc0 = 0.f, acc1 = 0.f, acc2 = 0.f, acc3 = 0.f;
    #pragma unroll 2
    for (int k = 0; k < K; k += 4) {
        const float x0 = xT[(k+0)*64 + n];
        const float x1 = xT[(k+1)*64 + n];
        const float x2 = xT[(k+2)*64 + n];
        const float x3 = xT[(k+3)*64 + n];
        const float4 w0 = *reinterpret_cast<const float4*>(Wr + (size_t)0*K + k);
        const float4 w1 = *reinterpret_cast<const float4*>(Wr + (size_t)1*K + k);
        const float4 w2 = *reinterpret_cast<const float4*>(Wr + (size_t)2*K + k);
        const float4 w3 = *reinterpret_cast<const float4*>(Wr + (size_t)3*K + k);
        acc0 = fmaf(x3, w0.w, fmaf(x2, w0.z, fmaf(x1, w0.y, fmaf(x0, w0.x, acc0))));
        acc1 = fmaf(x3, w1.w, fmaf(x2, w1.z, fmaf(x1, w1.y, fmaf(x0, w1.x, acc1))));
        acc2 = fmaf(x3, w2.w, fmaf(x2, w2.z, fmaf(x1, w2.y, fmaf(x0, w2.x, acc2))));
        acc3 = fmaf(x3, w3.w, fmaf(x2, w3.z, fmaf(x1, w3.y, fmaf(x0, w3.x, acc3))));
    }
    acc0 += b1[j0+0] + b2[j0+0];
    acc1 += b1[j0+1] + b2[j0+1];
    acc2 += b1[j0+2] + b2[j0+2];
    acc3 += b1[j0+3] + b2[j0+3];
    outT[(jj0+0)*64 + n] = acc0;
    outT[(jj0+1)*64 + n] = acc1;
    outT[(jj0+2)*64 + n] = acc2;
    outT[(jj0+3)*64 + n] = acc3;
}

// h = sigmoid(o)*tanh(sigmoid(i)*tanh(g)); gates compact rows i|g|o
__global__ void lstm_act_kernel(const float* __restrict__ gT, float* __restrict__ hT,
                                float* __restrict__ dec_out)
{
    const int idx = blockIdx.x * 256 + threadIdx.x;   // 64*2048 threads
    const int n = idx & 63;
    const int m = idx >> 6;
    const float gi = gT[idx];
    const float gg = gT[2048*64 + idx];
    const float go = gT[4096*64 + idx];
    const float c = sigmoidf_(gi) * tanhf(gg);
    const float h = sigmoidf_(go) * tanhf(c);
    hT[idx] = h;
    if (dec_out) dec_out[n*2560 + m] = h;
}

// output = dec_output @ Wo + bo   (K=2560 -> J=160, K-major Wo)
__global__ void final_kernel(const float* __restrict__ h2T, const float* __restrict__ ctxT,
                             const float* __restrict__ Wo, const float* __restrict__ bo,
                             float* __restrict__ out)
{
    const int tid = threadIdx.x;
    const int n = tid & 63;
    const int j = blockIdx.x * 4 + (tid >> 6);   // j < 160
    float acc = 0.f;
    for (int k = 0; k < 2048; ++k) acc = fmaf(h2T[k*64 + n], Wo[k*160 + j], acc);
    for (int k = 0; k < 512; ++k)  acc = fmaf(ctxT[k*64 + n], Wo[(2048 + k)*160 + j], acc);
    out[n*160 + j] = acc + bo[j];
}

extern "C" void kernel_launch(void* const* d_in, const int* in_sizes, int n_in,
                              void* d_out, int out_size, void* d_ws, size_t ws_size,
                              hipStream_t stream)
{
    const float* input_enc = (const float*)d_in[0];
    const float* input_dec = (const float*)d_in[1];
    const float* spkr      = (const float*)d_in[2];
    const float* speed     = (const float*)d_in[3];
    const int*   lengths   = (const int*)  d_in[4];
    const float* We        = (const float*)d_in[5];
    const float* be        = (const float*)d_in[6];
    const float* Ws        = (const float*)d_in[7];
    const float* conv_w    = (const float*)d_in[8];
    const float* w_proj    = (const float*)d_in[9];
    const float* b_proj    = (const float*)d_in[10];
    const float* W_speed   = (const float*)d_in[11];
    const float* sp_W1     = (const float*)d_in[12];
    const float* sp_b1     = (const float*)d_in[13];
    const float* sp_W2     = (const float*)d_in[14];
    const float* sp_b2     = (const float*)d_in[15];
    const float* pre_W1    = (const float*)d_in[16];
    const float* pre_b1    = (const float*)d_in[17];
    const float* pre_W2    = (const float*)d_in[18];
    const float* pre_b2    = (const float*)d_in[19];
    const float* Wih0      = (const float*)d_in[20];
    const float* bih0      = (const float*)d_in[22];
    const float* bhh0      = (const float*)d_in[23];
    const float* Wih1      = (const float*)d_in[24];
    const float* bih1      = (const float*)d_in[26];
    const float* bhh1      = (const float*)d_in[27];
    const float* Wo        = (const float*)d_in[28];
    const float* bo        = (const float*)d_in[29];

    float* ws  = (float*)d_ws;
    float* XT0 = ws;                  // 1088*64
    float* G   = ws + 69632;          // 6144*64 (reused for both LSTM layers)
    float* XT1 = ws + 462848;         // 2048*64 (h1^T then h2^T)
    float* HID = ws + 593920;         // 1024*64
    float* SPT = ws + 659456;         // 512*64

    float* out     = (float*)d_out;   // output: 64*2*80 = 10240
    float* out_ctx = out + 10240;     // context: 64*512
    float* out_dec = out + 43008;     // dec_output: 64*2560

    hidden_kernel<<<256, 256, 0, stream>>>(input_dec, spkr, pre_W1, pre_b1, HID);
    sp_kernel<<<128, 256, 0, stream>>>(speed, sp_W1, sp_b1, sp_W2, sp_b2, SPT);
    p_kernel<<<128, 256, 0, stream>>>(HID, pre_W2, pre_b2, XT0);
    attn_kernel<<<64, 256, 0, stream>>>(input_enc, spkr, speed, lengths, We, be, Ws, conv_w,
                                        w_proj, b_proj, W_speed, SPT, XT0, out_ctx, out_dec);
    gemm_big<1088, true><<<384, 256, 0, stream>>>(XT0, Wih0, bih0, bhh0, G);
    lstm_act_kernel<<<512, 256, 0, stream>>>(G, XT1, nullptr);
    gemm_big<2048, true><<<384, 256, 0, stream>>>(XT1, Wih1, bih1, bhh1, G);
    lstm_act_kernel<<<512, 256, 0, stream>>>(G, XT1, out_dec);
    final_kernel<<<40, 256, 0, stream>>>(XT1, XT0 + 512*64, Wo, bo, out);
}

// Round 2
// 968.058 us; speedup vs baseline: 1.0252x; 1.0252x over previous
//
#include <hip/hip_runtime.h>
#include <math.h>

// N=64, T=2048, E=512, A=256, D=512, S=64, O=80, H4=2048
// Algebraic facts exploited:
//  - att0 one-hot at t=0 -> attention window = t in [0,10); softmax max-shift cancels
//  - h=c=0 into both LSTM cells -> Whh* unused; f-gate rows of Wih* unused
//  - conv(one-hot) = conv_w[a, 15-t]
//
// ws layout (floats):
//   XT0 @ 0       : 1088*64  in_lstm^T (k-major: rows 0..512 prenet p | 512..1024 ctx | 1024..1088 spkr)
//   G   @ 69632   : 6144*64  gates^T compact (i | g | o), reused both layers
//   XT1 @ 462848  : 2048*64  h1^T then h2^T
//   HID @ 593920  : 64*1024  prenet hidden, n-major
//   SP  @ 659456  : 64*512   sp, n-major

__device__ __forceinline__ float sigmoidf_(float x){ return 1.0f/(1.0f+expf(-x)); }
__device__ __forceinline__ float softsignf_(float x){ return x/(1.0f+fabsf(x)); }

// ---- Pattern A small GEMMs: block = one n (x loads scalar-uniform), threads = j (W coalesced)

// hidden[n,j] = relu(concat(input_dec,spkr)[n,:] @ pre_W1 + pre_b1), J=1024, K=144
__global__ void hidden_kernel(const float* __restrict__ input_dec, const float* __restrict__ spkr,
                              const float* __restrict__ W, const float* __restrict__ b,
                              float* __restrict__ hid)
{
    const int n = blockIdx.x;
    const int j = blockIdx.y * 256 + threadIdx.x;   // < 1024
    float a0=0.f, a1=0.f, a2=0.f, a3=0.f;
    #pragma unroll 4
    for (int k = 0; k < 144; k += 4) {
        const float x0 = (k+0 < 80) ? input_dec[n*80 + k+0] : spkr[n*64 + (k+0-80)];
        const float x1 = (k+1 < 80) ? input_dec[n*80 + k+1] : spkr[n*64 + (k+1-80)];
        const float x2 = (k+2 < 80) ? input_dec[n*80 + k+2] : spkr[n*64 + (k+2-80)];
        const float x3 = (k+3 < 80) ? input_dec[n*80 + k+3] : spkr[n*64 + (k+3-80)];
        a0 = fmaf(x0, W[(k+0)*1024 + j], a0);
        a1 = fmaf(x1, W[(k+1)*1024 + j], a1);
        a2 = fmaf(x2, W[(k+2)*1024 + j], a2);
        a3 = fmaf(x3, W[(k+3)*1024 + j], a3);
    }
    hid[n*1024 + j] = fmaxf((a0+a1)+(a2+a3) + b[j], 0.f);
}

// sp[n,j] = tanh(relu(speed*sp_W1+sp_b1) @ sp_W2 + sp_b2), J=512, K=512
__global__ void sp_kernel(const float* __restrict__ speed, const float* __restrict__ sp_W1,
                          const float* __restrict__ sp_b1, const float* __restrict__ sp_W2,
                          const float* __restrict__ sp_b2, float* __restrict__ sp)
{
    const int n = blockIdx.x;
    const int j = blockIdx.y * 256 + threadIdx.x;   // < 512
    const float s = speed[n];
    float a0=0.f, a1=0.f, a2=0.f, a3=0.f;
    #pragma unroll 4
    for (int d = 0; d < 512; d += 4) {
        const float r0 = fmaxf(fmaf(s, sp_W1[d+0], sp_b1[d+0]), 0.f);
        const float r1 = fmaxf(fmaf(s, sp_W1[d+1], sp_b1[d+1]), 0.f);
        const float r2 = fmaxf(fmaf(s, sp_W1[d+2], sp_b1[d+2]), 0.f);
        const float r3 = fmaxf(fmaf(s, sp_W1[d+3], sp_b1[d+3]), 0.f);
        a0 = fmaf(r0, sp_W2[(d+0)*512 + j], a0);
        a1 = fmaf(r1, sp_W2[(d+1)*512 + j], a1);
        a2 = fmaf(r2, sp_W2[(d+2)*512 + j], a2);
        a3 = fmaf(r3, sp_W2[(d+3)*512 + j], a3);
    }
    sp[n*512 + j] = tanhf((a0+a1)+(a2+a3) + sp_b2[j]);
}

// p[n,j] = relu(hid[n,:] @ pre_W2 + pre_b2) -> XT0 rows [0,512), J=512, K=1024
__global__ void p_kernel(const float* __restrict__ hid, const float* __restrict__ W,
                         const float* __restrict__ b, float* __restrict__ xT0)
{
    const int n = blockIdx.x;
    const int j = blockIdx.y * 256 + threadIdx.x;   // < 512
    const float* xr = hid + n*1024;
    float a0=0.f, a1=0.f, a2=0.f, a3=0.f;
    #pragma unroll 4
    for (int k = 0; k < 1024; k += 4) {
        a0 = fmaf(xr[k+0], W[(k+0)*512 + j], a0);
        a1 = fmaf(xr[k+1], W[(k+1)*512 + j], a1);
        a2 = fmaf(xr[k+2], W[(k+2)*512 + j], a2);
        a3 = fmaf(xr[k+3], W[(k+3)*512 + j], a3);
    }
    xT0[j*64 + n] = fmaxf((a0+a1)+(a2+a3) + b[j], 0.f);
}

// attention + context, one block per batch row n, 256 threads (= a index)
__global__ void attn_kernel(const float* __restrict__ input_enc,
                            const float* __restrict__ spkr,
                            const float* __restrict__ speed,
                            const int*   __restrict__ lengths,
                            const float* __restrict__ We,
                            const float* __restrict__ be,
                            const float* __restrict__ Ws,
                            const float* __restrict__ conv_w,
                            const float* __restrict__ w_proj,
                            const float* __restrict__ b_proj,
                            const float* __restrict__ W_speed,
                            const float* __restrict__ sp,
                            float* __restrict__ xT0,
                            float* __restrict__ out_ctx,
                            float* __restrict__ out_dec)
{
    const int n = blockIdx.x;
    const int a = threadIdx.x;               // 256 threads
    __shared__ float encs[10*512];           // 20 KB
    __shared__ float part[4][10];
    __shared__ float logit_s[10];
    __shared__ float att_s[10];

    const int L1 = lengths[n] - 1;
    const int tc = (L1 + 1 < 10) ? (L1 + 1) : 10;
    const float sn = speed[n];
    const float* enc_n = input_enc + (size_t)n * (2048*512);

    for (int idx = a; idx < 10*512; idx += 256) encs[idx] = enc_n[idx];
    __syncthreads();

    float ds = 0.f;
    for (int s = 0; s < 64; ++s) ds = fmaf(spkr[n*64 + s], Ws[s*256 + a], ds);
    const float bspkr = softsignf_(ds);
    const float bspd  = sn * W_speed[a];
    const float bea   = be[a];
    const float wpa   = w_proj[a];

    float dt[10];
    #pragma unroll
    for (int t = 0; t < 10; ++t) dt[t] = 0.f;
    for (int k = 0; k < 512; ++k) {
        const float w = We[k*256 + a];
        #pragma unroll
        for (int t = 0; t < 10; ++t) dt[t] = fmaf(encs[t*512 + k], w, dt[t]);
    }

    for (int t = 0; t < 10; ++t) {
        float e = softsignf_(dt[t] + bea);
        e += bspkr + conv_w[a*31 + (15 - t)] + bspd;
        float v = tanhf(e) * wpa;
        #pragma unroll
        for (int off = 32; off > 0; off >>= 1) v += __shfl_down(v, off);
        if ((a & 63) == 0) part[a >> 6][t] = v;
    }
    __syncthreads();
    if (a < 10) logit_s[a] = part[0][a] + part[1][a] + part[2][a] + part[3][a] + b_proj[0];
    __syncthreads();
    if (a == 0) {
        float mx = -1e30f;
        for (int t = 0; t < tc; ++t) mx = fmaxf(mx, logit_s[t]);
        float ssum = 0.f;
        for (int t = 0; t < tc; ++t) { att_s[t] = expf(logit_s[t] - mx); ssum += att_s[t]; }
        const float inv = 1.f / fmaxf(ssum, 1e-12f);
        for (int t = 0; t < tc; ++t) att_s[t] *= inv;
        for (int t = tc; t < 10; ++t) att_s[t] = 0.f;
    }
    __syncthreads();

    for (int e0 = a; e0 < 512; e0 += 256) {
        const float spv = sp[n*512 + e0];
        float c = 0.f;
        for (int t = 0; t < tc; ++t) c = fmaf(att_s[t], encs[t*512 + e0] + spv, c);
        xT0[(512 + e0)*64 + n] = c;
        out_ctx[n*512 + e0]   = c;
        out_dec[n*2560 + 2048 + e0] = c;
    }
    if (a < 64) xT0[(1024 + a)*64 + n] = spkr[n*64 + a];
}

// big skinny GEMM: lanes = n, 2 waves/block, 4 rows/thread -> 8 rows/block, 768 blocks
template<int K, bool FSKIP>
__global__ void gemm_big(const float* __restrict__ xT, const float* __restrict__ W,
                         const float* __restrict__ b1, const float* __restrict__ b2,
                         float* __restrict__ outT)
{
    const int tid = threadIdx.x;              // 128 threads
    const int n = tid & 63;
    const int wv = __builtin_amdgcn_readfirstlane(tid >> 6);
    const int jj0 = blockIdx.x * 8 + wv * 4;
    const int j0  = (FSKIP && jj0 >= 2048) ? jj0 + 2048 : jj0;
    const float* Wr = W + (size_t)j0 * K;
    float acc0 = 0.f, acc1 = 0.f, acc2 = 0.f, acc3 = 0.f;
    #pragma unroll 2
    for (int k = 0; k < K; k += 4) {
        const float x0 = xT[(k+0)*64 + n];
        const float x1 = xT[(k+1)*64 + n];
        const float x2 = xT[(k+2)*64 + n];
        const float x3 = xT[(k+3)*64 + n];
        const float4 w0 = *reinterpret_cast<const float4*>(Wr + (size_t)0*K + k);
        const float4 w1 = *reinterpret_cast<const float4*>(Wr + (size_t)1*K + k);
        const float4 w2 = *reinterpret_cast<const float4*>(Wr + (size_t)2*K + k);
        const float4 w3 = *reinterpret_cast<const float4*>(Wr + (size_t)3*K + k);
        acc0 = fmaf(x3, w0.w, fmaf(x2, w0.z, fmaf(x1, w0.y, fmaf(x0, w0.x, acc0))));
        acc1 = fmaf(x3, w1.w, fmaf(x2, w1.z, fmaf(x1, w1.y, fmaf(x0, w1.x, acc1))));
        acc2 = fmaf(x3, w2.w, fmaf(x2, w2.z, fmaf(x1, w2.y, fmaf(x0, w2.x, acc2))));
        acc3 = fmaf(x3, w3.w, fmaf(x2, w3.z, fmaf(x1, w3.y, fmaf(x0, w3.x, acc3))));
    }
    acc0 += b1[j0+0] + b2[j0+0];
    acc1 += b1[j0+1] + b2[j0+1];
    acc2 += b1[j0+2] + b2[j0+2];
    acc3 += b1[j0+3] + b2[j0+3];
    outT[(jj0+0)*64 + n] = acc0;
    outT[(jj0+1)*64 + n] = acc1;
    outT[(jj0+2)*64 + n] = acc2;
    outT[(jj0+3)*64 + n] = acc3;
}

// h = sigmoid(o)*tanh(sigmoid(i)*tanh(g)); gates compact rows i|g|o
__global__ void lstm_act_kernel(const float* __restrict__ gT, float* __restrict__ hT,
                                float* __restrict__ dec_out)
{
    const int idx = blockIdx.x * 256 + threadIdx.x;   // 64*2048
    const int n = idx & 63;
    const int m = idx >> 6;
    const float gi = gT[idx];
    const float gg = gT[2048*64 + idx];
    const float go = gT[4096*64 + idx];
    const float c = sigmoidf_(gi) * tanhf(gg);
    const float h = sigmoidf_(go) * tanhf(c);
    hT[idx] = h;
    if (dec_out) dec_out[n*2560 + m] = h;
}

// out[n,j] = dec_output[n,:] @ Wo + bo  (Pattern A: block=n, threads=j<160, Wo coalesced)
__global__ void final_kernel(const float* __restrict__ h2T, const float* __restrict__ ctx,
                             const float* __restrict__ Wo, const float* __restrict__ bo,
                             float* __restrict__ out)
{
    const int n = blockIdx.x;
    const int j = threadIdx.x;                // 256 threads, 160 active
    if (j >= 160) return;
    float a0=0.f, a1=0.f, a2=0.f, a3=0.f;
    #pragma unroll 4
    for (int k = 0; k < 2048; k += 4) {
        a0 = fmaf(h2T[(k+0)*64 + n], Wo[(k+0)*160 + j], a0);
        a1 = fmaf(h2T[(k+1)*64 + n], Wo[(k+1)*160 + j], a1);
        a2 = fmaf(h2T[(k+2)*64 + n], Wo[(k+2)*160 + j], a2);
        a3 = fmaf(h2T[(k+3)*64 + n], Wo[(k+3)*160 + j], a3);
    }
    const float* cr = ctx + n*512;
    #pragma unroll 4
    for (int k = 0; k < 512; k += 4) {
        a0 = fmaf(cr[k+0], Wo[(2048+k+0)*160 + j], a0);
        a1 = fmaf(cr[k+1], Wo[(2048+k+1)*160 + j], a1);
        a2 = fmaf(cr[k+2], Wo[(2048+k+2)*160 + j], a2);
        a3 = fmaf(cr[k+3], Wo[(2048+k+3)*160 + j], a3);
    }
    out[n*160 + j] = (a0+a1)+(a2+a3) + bo[j];
}

extern "C" void kernel_launch(void* const* d_in, const int* in_sizes, int n_in,
                              void* d_out, int out_size, void* d_ws, size_t ws_size,
                              hipStream_t stream)
{
    const float* input_enc = (const float*)d_in[0];
    const float* input_dec = (const float*)d_in[1];
    const float* spkr      = (const float*)d_in[2];
    const float* speed     = (const float*)d_in[3];
    const int*   lengths   = (const int*)  d_in[4];
    const float* We        = (const float*)d_in[5];
    const float* be        = (const float*)d_in[6];
    const float* Ws        = (const float*)d_in[7];
    const float* conv_w    = (const float*)d_in[8];
    const float* w_proj    = (const float*)d_in[9];
    const float* b_proj    = (const float*)d_in[10];
    const float* W_speed   = (const float*)d_in[11];
    const float* sp_W1     = (const float*)d_in[12];
    const float* sp_b1     = (const float*)d_in[13];
    const float* sp_W2     = (const float*)d_in[14];
    const float* sp_b2     = (const float*)d_in[15];
    const float* pre_W1    = (const float*)d_in[16];
    const float* pre_b1    = (const float*)d_in[17];
    const float* pre_W2    = (const float*)d_in[18];
    const float* pre_b2    = (const float*)d_in[19];
    const float* Wih0      = (const float*)d_in[20];
    const float* bih0      = (const float*)d_in[22];
    const float* bhh0      = (const float*)d_in[23];
    const float* Wih1      = (const float*)d_in[24];
    const float* bih1      = (const float*)d_in[26];
    const float* bhh1      = (const float*)d_in[27];
    const float* Wo        = (const float*)d_in[28];
    const float* bo        = (const float*)d_in[29];

    float* ws  = (float*)d_ws;
    float* XT0 = ws;                  // 1088*64
    float* G   = ws + 69632;          // 6144*64
    float* XT1 = ws + 462848;         // 2048*64
    float* HID = ws + 593920;         // 64*1024 (n-major)
    float* SP  = ws + 659456;         // 64*512  (n-major)

    float* out     = (float*)d_out;   // 64*2*80
    float* out_ctx = out + 10240;     // 64*512
    float* out_dec = out + 43008;     // 64*2560

    hidden_kernel<<<dim3(64,4), 256, 0, stream>>>(input_dec, spkr, pre_W1, pre_b1, HID);
    sp_kernel<<<dim3(64,2), 256, 0, stream>>>(speed, sp_W1, sp_b1, sp_W2, sp_b2, SP);
    p_kernel<<<dim3(64,2), 256, 0, stream>>>(HID, pre_W2, pre_b2, XT0);
    attn_kernel<<<64, 256, 0, stream>>>(input_enc, spkr, speed, lengths, We, be, Ws, conv_w,
                                        w_proj, b_proj, W_speed, SP, XT0, out_ctx, out_dec);
    gemm_big<1088, true><<<768, 128, 0, stream>>>(XT0, Wih0, bih0, bhh0, G);
    lstm_act_kernel<<<512, 256, 0, stream>>>(G, XT1, nullptr);
    gemm_big<2048, true><<<768, 128, 0, stream>>>(XT1, Wih1, bih1, bhh1, G);
    lstm_act_kernel<<<512, 256, 0, stream>>>(G, XT1, out_dec);
    final_kernel<<<64, 256, 0, stream>>>(XT1, out_ctx, Wo, bo, out);
}